// Round 6
// baseline (348.806 us; speedup 1.0000x reference)
//
#include <hip/hip_runtime.h>

#define HEADS 24
#define KVH   6
#define HD    64
#define BB    2
#define SS    2048
#define DD    1536
#define KVD   384      // KVH*HD
#define NTOT  2304     // DD + 2*KVD
#define MM    4096     // BB*SS

typedef unsigned short ushort_t;
typedef __attribute__((ext_vector_type(8))) short short8;
typedef __attribute__((ext_vector_type(4))) float f32x4;

__device__ __forceinline__ ushort_t f2bf(float f) {
    union { float f; unsigned u; } v; v.f = f;
    return (ushort_t)((v.u + 0x8000u) >> 16);
}
__device__ __forceinline__ ushort_t f2bf_trunc(float f) {
    union { float f; unsigned u; } v; v.f = f;
    return (ushort_t)(v.u >> 16);
}
__device__ __forceinline__ unsigned pk2(float a, float b) {
    union { float f; unsigned u; } x, y; x.f = a; y.f = b;
    return ((x.u + 0x8000u) >> 16) | (((y.u + 0x8000u) >> 16) << 16);
}
#if __has_builtin(__builtin_amdgcn_exp2f)
#define EXP2(x) __builtin_amdgcn_exp2f(x)
#else
#define EXP2(x) exp2f(x)
#endif
// async global->LDS, 16B per lane; lds ptr must be wave-uniform base.
__device__ __forceinline__ void glds16(const void* g, void* l) {
    __builtin_amdgcn_global_load_lds(
        (const __attribute__((address_space(1))) void*)g,
        (__attribute__((address_space(3))) void*)l, 16, 0, 0);
}

// ---------------------------------------------------------------------------
// K0: fused preprocessing — one launch replaces k_cvt + 4x k_tconv.
// Range-dispatch on blockIdx.x: [0,6144) cvt HS->Xbf; then W transposes.
// ---------------------------------------------------------------------------
__device__ __forceinline__ void tconv_body(const float* __restrict__ in,
                                           ushort_t* __restrict__ out,
                                           int R, int C, int cb, int rb)
{
    __shared__ ushort_t tile[32][33];
    const int tx = threadIdx.x & 31, ty = threadIdx.x >> 5;
    const int c0 = cb * 32, r0 = rb * 32;
#pragma unroll
    for (int i = 0; i < 4; ++i)
        tile[ty + i * 8][tx] = f2bf(in[(size_t)(r0 + ty + i * 8) * C + c0 + tx]);
    __syncthreads();
#pragma unroll
    for (int i = 0; i < 4; ++i)
        out[(size_t)(c0 + ty + i * 8) * R + r0 + tx] = tile[tx][ty + i * 8];
}

#define NCVT (MM * DD / 4 / 256)     // 6144
__global__ __launch_bounds__(256) void k_prep(const float* __restrict__ HS,
                                              const float* __restrict__ Wq,
                                              const float* __restrict__ Wk,
                                              const float* __restrict__ Wv,
                                              const float* __restrict__ Wo,
                                              ushort_t* __restrict__ Xbf,
                                              ushort_t* __restrict__ Wqt,
                                              ushort_t* __restrict__ Wkt,
                                              ushort_t* __restrict__ Wvt,
                                              ushort_t* __restrict__ Wot)
{
    int bid = blockIdx.x;
    if (bid < NCVT) {
        int i = bid * 256 + threadIdx.x;
        float4 v = ((const float4*)HS)[i];
        uint2 o = { pk2(v.x, v.y), pk2(v.z, v.w) };
        ((uint2*)Xbf)[i] = o;
        return;
    }
    bid -= NCVT;
    if (bid < 2304) { tconv_body(Wq, Wqt, DD, DD,  bid % 48, bid / 48); return; }
    bid -= 2304;
    if (bid < 576)  { tconv_body(Wk, Wkt, DD, KVD, bid % 12, bid / 12); return; }
    bid -= 576;
    if (bid < 576)  { tconv_body(Wv, Wvt, DD, KVD, bid % 12, bid / 12); return; }
    bid -= 576;
    tconv_body(Wo, Wot, DD, DD, bid % 48, bid / 48);
}

// ---------------------------------------------------------------------------
// Transpose V region of QKVb (bf16) -> VT[b][KVD][SS] (bf16)
// ---------------------------------------------------------------------------
__global__ __launch_bounds__(256) void k_vt(const ushort_t* __restrict__ QKVb,
                                            ushort_t* __restrict__ VT)
{
    __shared__ ushort_t tile[32][33];
    const int tx = threadIdx.x & 31, ty = threadIdx.x >> 5;
    const int s0 = blockIdx.x * 32, c0 = blockIdx.y * 32, b = blockIdx.z;
#pragma unroll
    for (int i = 0; i < 4; ++i)
        tile[ty + i * 8][tx] =
            QKVb[(size_t)(b * SS + s0 + ty + i * 8) * NTOT + DD + KVD + c0 + tx];
    __syncthreads();
#pragma unroll
    for (int i = 0; i < 4; ++i)
        VT[((size_t)b * KVD + c0 + ty + i * 8) * SS + s0 + tx] = tile[tx][ty + i * 8];
}

// ---------------------------------------------------------------------------
// K1: MFMA QKV projection + fused partial RoPE + fused Q-scale.
// Q scale = (1/8)*log2(e) so attention can use 2^s = e^(q.k/8) directly.
// ---------------------------------------------------------------------------
__global__ __launch_bounds__(256) void k_qkv_mfma(const ushort_t* __restrict__ Xbf,
                                                  const ushort_t* __restrict__ Wqt,
                                                  const ushort_t* __restrict__ Wkt,
                                                  const ushort_t* __restrict__ Wvt,
                                                  const float* __restrict__ cosb,
                                                  const float* __restrict__ sinb,
                                                  ushort_t* __restrict__ QKVb)
{
    __shared__ ushort_t As[128][32];
    __shared__ ushort_t Bs[128][32];
    const int t = threadIdx.x, lane = t & 63, wave = t >> 6;
    const int n16 = lane & 15, quad = lane >> 4;
    const int wr = wave >> 1, wc = wave & 1;
    const int nt = blockIdx.x;
    const int n0 = nt * 128;
    const int m0 = blockIdx.y * 128;
    const ushort_t* Bt; int nl, mode;    // 0=Q (rope+scale), 1=K (rope), 2=V
    if (nt < 12)      { Bt = Wqt; nl = n0;            mode = 0; }
    else if (nt < 15) { Bt = Wkt; nl = n0 - DD;       mode = 1; }
    else              { Bt = Wvt; nl = n0 - DD - KVD; mode = 2; }

    const int srow = lane >> 2;
    const int scol = (lane & 3) * 8;
    const size_t aoff0 = (size_t)(m0 + wave * 16 + srow) * DD + scol;
    const size_t aoff1 = (size_t)(m0 + (wave + 4) * 16 + srow) * DD + scol;
    const size_t boff0 = (size_t)(nl + wave * 16 + srow) * DD + scol;
    const size_t boff1 = (size_t)(nl + (wave + 4) * 16 + srow) * DD + scol;
    ushort_t* lA0 = &As[wave * 16][0];
    ushort_t* lA1 = &As[(wave + 4) * 16][0];
    ushort_t* lB0 = &Bs[wave * 16][0];
    ushort_t* lB1 = &Bs[(wave + 4) * 16][0];

    f32x4 acc[4][4] = {};
    for (int k0 = 0; k0 < DD; k0 += 32) {
        __syncthreads();
        glds16(Xbf + aoff0 + k0, lA0);
        glds16(Xbf + aoff1 + k0, lA1);
        glds16(Bt  + boff0 + k0, lB0);
        glds16(Bt  + boff1 + k0, lB1);
        __syncthreads();
        short8 af[4], bf8[4];
#pragma unroll
        for (int i = 0; i < 4; ++i) af[i]  = *(const short8*)&As[wr * 64 + i * 16 + n16][quad * 8];
#pragma unroll
        for (int j = 0; j < 4; ++j) bf8[j] = *(const short8*)&Bs[wc * 64 + j * 16 + n16][quad * 8];
#pragma unroll
        for (int i = 0; i < 4; ++i)
#pragma unroll
            for (int j = 0; j < 4; ++j)
                acc[i][j] = __builtin_amdgcn_mfma_f32_16x16x32_bf16(af[i], bf8[j], acc[i][j], 0, 0, 0);
    }

    const float QSC = 0.18033688011112042f;   // 0.125 * log2(e)
#pragma unroll
    for (int i = 0; i < 4; ++i) {
#pragma unroll
        for (int r = 0; r < 4; ++r) {
            const int row = m0 + wr * 64 + i * 16 + quad * 4 + r;
            ushort_t* outp = QKVb + (size_t)row * NTOT + n0 + wc * 64 + n16;
            float v0 = acc[i][0][r], v1 = acc[i][1][r];
            float v2 = acc[i][2][r], v3 = acc[i][3][r];
            if (mode < 2) {            // partial RoPE on head dims 0..31
                const int s = row & (SS - 1);
                float c0 = cosb[s * 32 + n16],      s0 = sinb[s * 32 + n16];
                float c1 = cosb[s * 32 + 16 + n16], s1 = sinb[s * 32 + 16 + n16];
                float nr = v0 * c0 - v1 * s0;
                float ni = v1 * c1 + v0 * s1;
                v0 = nr; v1 = ni;
            }
            if (mode == 0) { v0 *= QSC; v1 *= QSC; v2 *= QSC; v3 *= QSC; }
            outp[0]  = f2bf(v0);
            outp[16] = f2bf(v1);
            outp[32] = f2bf(v2);
            outp[48] = f2bf(v3);
        }
    }
}

// ---------------------------------------------------------------------------
// K3: MFMA bf16 flash attention, NO-MAX softmax, 64 q-rows PER WAVE.
// Block = 2 waves x 128 q-rows x 1 head.  K/V frag reads amortize over 2x
// MFMA vs the 32q/wave version (LDS cyc/q-row 13.0 -> 9.25).
// K [ktok][d] stride 72; V [d][ktok] from pre-transposed VT; P stride 76.
// LDS 37.9 KB; grid 768 blocks = 3 blocks/CU = 6 waves/CU.
// ---------------------------------------------------------------------------
__global__ __launch_bounds__(128) void k_attn(const ushort_t* __restrict__ QKVb,
                                              const ushort_t* __restrict__ VT,
                                              ushort_t* __restrict__ AOb)
{
    __shared__ __align__(16) ushort_t Ks[64][72];
    __shared__ __align__(16) ushort_t Vs[64][72];   // Vs[d][ktok]
    __shared__ __align__(16) ushort_t Ps[128][76];

    const int t    = threadIdx.x;
    const int wave = t >> 6;          // 0..1
    const int quad = (t >> 4) & 3;
    const int n16  = t & 15;
    const int q0   = blockIdx.x * 128;
    const int h    = blockIdx.y;
    const int b    = blockIdx.z;
    const int kh   = h >> 2;

    const int sr  = t >> 1;           // 0..63 staging row
    const int scE = (t & 1) * 32;     // staging col (elements), 32 per thread

    // loop-invariant Q A-frags from global (pre-scaled by 0.125*log2e)
    short8 qf[4][2];
#pragma unroll
    for (int m = 0; m < 4; ++m)
#pragma unroll
        for (int kc = 0; kc < 2; ++kc)
            qf[m][kc] = *(const short8*)(QKVb +
                (size_t)(b * SS + q0 + wave * 64 + m * 16 + n16) * NTOT +
                h * HD + kc * 32 + quad * 8);

    float l_p[4][4] = {};             // per-lane partial row sums
    f32x4 acc_o[4][4] = {};

    const ushort_t* Kbase = QKVb + (size_t)(b * SS) * NTOT + DD + kh * HD;
    const ushort_t* Vbase = VT + ((size_t)b * KVD + kh * 64) * SS;

    for (int kt = 0; kt < SS / 64; ++kt) {
        const int k0 = kt * 64;
        __syncthreads();   // prev-tile readers of Ks/Vs done
        {
            const ushort_t* Kg = Kbase + (size_t)(k0 + sr) * NTOT + scE;
            const ushort_t* Vg = Vbase + (size_t)sr * SS + k0 + scE;
#pragma unroll
            for (int u = 0; u < 4; ++u) {
                *(uint4*)&Ks[sr][scE + u * 8] = *(const uint4*)(Kg + u * 8);
                *(uint4*)&Vs[sr][scE + u * 8] = *(const uint4*)(Vg + u * 8);
            }
        }
        __syncthreads();

        // ---- QK^T: S[64q][64k] per wave ----
        f32x4 s_acc[4][4] = {};
#pragma unroll
        for (int kc = 0; kc < 2; ++kc) {
            short8 bf[4];
#pragma unroll
            for (int jj = 0; jj < 4; ++jj)
                bf[jj] = *(const short8*)&Ks[jj * 16 + n16][kc * 32 + quad * 8];
#pragma unroll
            for (int m = 0; m < 4; ++m)
#pragma unroll
                for (int jj = 0; jj < 4; ++jj)
                    s_acc[m][jj] = __builtin_amdgcn_mfma_f32_16x16x32_bf16(
                        qf[m][kc], bf[jj], s_acc[m][jj], 0, 0, 0);
        }

        // ---- p = 2^s; accumulate partial l; P -> wave-private LDS rows ----
#pragma unroll
        for (int m = 0; m < 4; ++m)
#pragma unroll
            for (int r = 0; r < 4; ++r) {
                float p0 = EXP2(s_acc[m][0][r]);
                float p1 = EXP2(s_acc[m][1][r]);
                float p2 = EXP2(s_acc[m][2][r]);
                float p3 = EXP2(s_acc[m][3][r]);
                ushort_t* pr = &Ps[wave * 64 + m * 16 + quad * 4 + r][n16];
                pr[0]  = f2bf_trunc(p0);
                pr[16] = f2bf_trunc(p1);
                pr[32] = f2bf_trunc(p2);
                pr[48] = f2bf_trunc(p3);
                l_p[m][r] += (p0 + p1) + (p2 + p3);
            }

        // ---- PV (Ps rows wave-private; same-wave RAW via lgkmcnt) ----
#pragma unroll
        for (int kc = 0; kc < 2; ++kc) {
            short8 vb[4];
#pragma unroll
            for (int dd = 0; dd < 4; ++dd)
                vb[dd] = *(const short8*)&Vs[dd * 16 + n16][kc * 32 + quad * 8];
#pragma unroll
            for (int m = 0; m < 4; ++m) {
                short8 pa = *(const short8*)&Ps[wave * 64 + m * 16 + n16][kc * 32 + quad * 8];
#pragma unroll
                for (int dd = 0; dd < 4; ++dd)
                    acc_o[m][dd] = __builtin_amdgcn_mfma_f32_16x16x32_bf16(
                        pa, vb[dd], acc_o[m][dd], 0, 0, 0);
            }
        }
    }

    // ---- epilogue: one lane-reduction of l, then O/l ----
#pragma unroll
    for (int m = 0; m < 4; ++m) {
        float inv[4];
#pragma unroll
        for (int r = 0; r < 4; ++r) {
            float s = l_p[m][r];
#pragma unroll
            for (int msk = 1; msk < 16; msk <<= 1)
                s += __shfl_xor(s, msk);
            inv[r] = 1.0f / s;
        }
#pragma unroll
        for (int dd = 0; dd < 4; ++dd)
#pragma unroll
            for (int r = 0; r < 4; ++r) {
                int q = q0 + wave * 64 + m * 16 + quad * 4 + r;
                AOb[(size_t)(b * SS + q) * DD + h * HD + dd * 16 + n16] =
                    f2bf(acc_o[m][dd][r] * inv[r]);
            }
    }
}

// ---------------------------------------------------------------------------
// K4: MFMA out-proj.  out[MM][DD](fp32) = AOb @ Wot^T + bo + HS
// ---------------------------------------------------------------------------
__global__ __launch_bounds__(256) void k_out_mfma(const ushort_t* __restrict__ AOb,
                                                  const ushort_t* __restrict__ Wot,
                                                  const float* __restrict__ bo,
                                                  const float* __restrict__ HS,
                                                  float* __restrict__ out)
{
    __shared__ ushort_t As[128][32];
    __shared__ ushort_t Bs[128][32];
    const int t = threadIdx.x, lane = t & 63, wave = t >> 6;
    const int n16 = lane & 15, quad = lane >> 4;
    const int wr = wave >> 1, wc = wave & 1;
    const int n0 = blockIdx.x * 128;
    const int m0 = blockIdx.y * 128;

    const int srow = lane >> 2;
    const int scol = (lane & 3) * 8;
    const size_t aoff0 = (size_t)(m0 + wave * 16 + srow) * DD + scol;
    const size_t aoff1 = (size_t)(m0 + (wave + 4) * 16 + srow) * DD + scol;
    const size_t boff0 = (size_t)(n0 + wave * 16 + srow) * DD + scol;
    const size_t boff1 = (size_t)(n0 + (wave + 4) * 16 + srow) * DD + scol;
    ushort_t* lA0 = &As[wave * 16][0];
    ushort_t* lA1 = &As[(wave + 4) * 16][0];
    ushort_t* lB0 = &Bs[wave * 16][0];
    ushort_t* lB1 = &Bs[(wave + 4) * 16][0];

    f32x4 acc[4][4] = {};
    for (int k0 = 0; k0 < DD; k0 += 32) {
        __syncthreads();
        glds16(AOb + aoff0 + k0, lA0);
        glds16(AOb + aoff1 + k0, lA1);
        glds16(Wot + boff0 + k0, lB0);
        glds16(Wot + boff1 + k0, lB1);
        __syncthreads();
        short8 af[4], bf8[4];
#pragma unroll
        for (int i = 0; i < 4; ++i) af[i]  = *(const short8*)&As[wr * 64 + i * 16 + n16][quad * 8];
#pragma unroll
        for (int j = 0; j < 4; ++j) bf8[j] = *(const short8*)&Bs[wc * 64 + j * 16 + n16][quad * 8];
#pragma unroll
        for (int i = 0; i < 4; ++i)
#pragma unroll
            for (int j = 0; j < 4; ++j)
                acc[i][j] = __builtin_amdgcn_mfma_f32_16x16x32_bf16(af[i], bf8[j], acc[i][j], 0, 0, 0);
    }

    const int colb = n0 + wc * 64 + n16;
    float bo4[4];
#pragma unroll
    for (int j = 0; j < 4; ++j) bo4[j] = bo[colb + j * 16];
#pragma unroll
    for (int i = 0; i < 4; ++i) {
#pragma unroll
        for (int r = 0; r < 4; ++r) {
            const int row = m0 + wr * 64 + i * 16 + quad * 4 + r;
            float* op = out + (size_t)row * DD + colb;
            const float* hp = HS + (size_t)row * DD + colb;
#pragma unroll
            for (int j = 0; j < 4; ++j)
                op[j * 16] = acc[i][j][r] + bo4[j] + hp[j * 16];
        }
    }
}

extern "C" void kernel_launch(void* const* d_in, const int* in_sizes, int n_in,
                              void* d_out, int out_size, void* d_ws, size_t ws_size,
                              hipStream_t stream)
{
    const float* HS   = (const float*)d_in[0];
    const float* cosb = (const float*)d_in[1];
    const float* sinb = (const float*)d_in[2];
    const float* Wq   = (const float*)d_in[3];
    const float* Wk   = (const float*)d_in[4];
    const float* Wv   = (const float*)d_in[5];
    const float* Wo   = (const float*)d_in[6];
    const float* bo   = (const float*)d_in[7];
    float* out = (float*)d_out;

    ushort_t* Xbf  = (ushort_t*)d_ws;                  // [MM][DD]
    ushort_t* QKVb = Xbf  + (size_t)MM * DD;           // [MM][NTOT]
    ushort_t* AOb  = QKVb + (size_t)MM * NTOT;         // [MM][DD]
    ushort_t* Wqt  = AOb  + (size_t)MM * DD;           // [DD][DD]
    ushort_t* Wkt  = Wqt  + (size_t)DD * DD;           // [KVD][DD]
    ushort_t* Wvt  = Wkt  + (size_t)KVD * DD;          // [KVD][DD]
    ushort_t* Wot  = Wvt  + (size_t)KVD * DD;          // [DD][DD]
    ushort_t* VT   = Wot  + (size_t)DD * DD;           // [BB][KVD][SS]

    const int nprep = NCVT + 2304 + 576 + 576 + 2304;
    k_prep    <<<dim3(nprep), 256, 0, stream>>>(HS, Wq, Wk, Wv, Wo,
                                                Xbf, Wqt, Wkt, Wvt, Wot);
    k_qkv_mfma<<<dim3(NTOT / 128, MM / 128), 256, 0, stream>>>(Xbf, Wqt, Wkt, Wvt, cosb, sinb, QKVb);
    k_vt      <<<dim3(SS / 32, KVD / 32, BB), 256, 0, stream>>>(QKVb, VT);
    k_attn    <<<dim3(SS / 128, HEADS, BB),   128, 0, stream>>>(QKVb, VT, AOb);
    k_out_mfma<<<dim3(DD / 128, MM / 128),    256, 0, stream>>>(AOb, Wot, bo, HS, out);
}

// Round 7
// 309.039 us; speedup vs baseline: 1.1287x; 1.1287x over previous
//
#include <hip/hip_runtime.h>

#define HEADS 24
#define KVH   6
#define HD    64
#define BB    2
#define SS    2048
#define DD    1536
#define KVD   384      // KVH*HD
#define NTOT  2304     // DD + 2*KVD
#define MM    4096     // BB*SS

typedef unsigned short ushort_t;
typedef __attribute__((ext_vector_type(8))) short short8;
typedef __attribute__((ext_vector_type(4))) float f32x4;

__device__ __forceinline__ ushort_t f2bf(float f) {
    union { float f; unsigned u; } v; v.f = f;
    return (ushort_t)((v.u + 0x8000u) >> 16);
}
__device__ __forceinline__ ushort_t f2bf_trunc(float f) {
    union { float f; unsigned u; } v; v.f = f;
    return (ushort_t)(v.u >> 16);
}
__device__ __forceinline__ unsigned pk2(float a, float b) {
    union { float f; unsigned u; } x, y; x.f = a; y.f = b;
    return ((x.u + 0x8000u) >> 16) | (((y.u + 0x8000u) >> 16) << 16);
}
#if __has_builtin(__builtin_amdgcn_exp2f)
#define EXP2(x) __builtin_amdgcn_exp2f(x)
#else
#define EXP2(x) exp2f(x)
#endif
// async global->LDS, 16B per lane; lds ptr must be wave-uniform base.
__device__ __forceinline__ void glds16(const void* g, void* l) {
    __builtin_amdgcn_global_load_lds(
        (const __attribute__((address_space(1))) void*)g,
        (__attribute__((address_space(3))) void*)l, 16, 0, 0);
}

// ---------------------------------------------------------------------------
// K0: fused preprocessing — one launch replaces cvt + 4x tconv.
// ---------------------------------------------------------------------------
__device__ __forceinline__ void tconv_body(const float* __restrict__ in,
                                           ushort_t* __restrict__ out,
                                           int R, int C, int cb, int rb)
{
    __shared__ ushort_t tile[32][33];
    const int tx = threadIdx.x & 31, ty = threadIdx.x >> 5;
    const int c0 = cb * 32, r0 = rb * 32;
#pragma unroll
    for (int i = 0; i < 4; ++i)
        tile[ty + i * 8][tx] = f2bf(in[(size_t)(r0 + ty + i * 8) * C + c0 + tx]);
    __syncthreads();
#pragma unroll
    for (int i = 0; i < 4; ++i)
        out[(size_t)(c0 + ty + i * 8) * R + r0 + tx] = tile[tx][ty + i * 8];
}

#define NCVT (MM * DD / 4 / 256)     // 6144
__global__ __launch_bounds__(256) void k_prep(const float* __restrict__ HS,
                                              const float* __restrict__ Wq,
                                              const float* __restrict__ Wk,
                                              const float* __restrict__ Wv,
                                              const float* __restrict__ Wo,
                                              ushort_t* __restrict__ Xbf,
                                              ushort_t* __restrict__ Wqt,
                                              ushort_t* __restrict__ Wkt,
                                              ushort_t* __restrict__ Wvt,
                                              ushort_t* __restrict__ Wot)
{
    int bid = blockIdx.x;
    if (bid < NCVT) {
        int i = bid * 256 + threadIdx.x;
        float4 v = ((const float4*)HS)[i];
        uint2 o = { pk2(v.x, v.y), pk2(v.z, v.w) };
        ((uint2*)Xbf)[i] = o;
        return;
    }
    bid -= NCVT;
    if (bid < 2304) { tconv_body(Wq, Wqt, DD, DD,  bid % 48, bid / 48); return; }
    bid -= 2304;
    if (bid < 576)  { tconv_body(Wk, Wkt, DD, KVD, bid % 12, bid / 12); return; }
    bid -= 576;
    if (bid < 576)  { tconv_body(Wv, Wvt, DD, KVD, bid % 12, bid / 12); return; }
    bid -= 576;
    tconv_body(Wo, Wot, DD, DD, bid % 48, bid / 48);
}

// ---------------------------------------------------------------------------
// Transpose V region of QKVb (bf16) -> VT[b][KVD][SS] (bf16)
// ---------------------------------------------------------------------------
__global__ __launch_bounds__(256) void k_vt(const ushort_t* __restrict__ QKVb,
                                            ushort_t* __restrict__ VT)
{
    __shared__ ushort_t tile[32][33];
    const int tx = threadIdx.x & 31, ty = threadIdx.x >> 5;
    const int s0 = blockIdx.x * 32, c0 = blockIdx.y * 32, b = blockIdx.z;
#pragma unroll
    for (int i = 0; i < 4; ++i)
        tile[ty + i * 8][tx] =
            QKVb[(size_t)(b * SS + s0 + ty + i * 8) * NTOT + DD + KVD + c0 + tx];
    __syncthreads();
#pragma unroll
    for (int i = 0; i < 4; ++i)
        VT[((size_t)b * KVD + c0 + ty + i * 8) * SS + s0 + tx] = tile[tx][ty + i * 8];
}

// ---------------------------------------------------------------------------
// K1: MFMA QKV projection + fused partial RoPE + fused Q-scale.
// Q scale = (1/8)*log2(e) so attention can use 2^s = e^(q.k/8) directly.
// ---------------------------------------------------------------------------
__global__ __launch_bounds__(256) void k_qkv_mfma(const ushort_t* __restrict__ Xbf,
                                                  const ushort_t* __restrict__ Wqt,
                                                  const ushort_t* __restrict__ Wkt,
                                                  const ushort_t* __restrict__ Wvt,
                                                  const float* __restrict__ cosb,
                                                  const float* __restrict__ sinb,
                                                  ushort_t* __restrict__ QKVb)
{
    __shared__ ushort_t As[128][32];
    __shared__ ushort_t Bs[128][32];
    const int t = threadIdx.x, lane = t & 63, wave = t >> 6;
    const int n16 = lane & 15, quad = lane >> 4;
    const int wr = wave >> 1, wc = wave & 1;
    const int nt = blockIdx.x;
    const int n0 = nt * 128;
    const int m0 = blockIdx.y * 128;
    const ushort_t* Bt; int nl, mode;    // 0=Q (rope+scale), 1=K (rope), 2=V
    if (nt < 12)      { Bt = Wqt; nl = n0;            mode = 0; }
    else if (nt < 15) { Bt = Wkt; nl = n0 - DD;       mode = 1; }
    else              { Bt = Wvt; nl = n0 - DD - KVD; mode = 2; }

    const int srow = lane >> 2;
    const int scol = (lane & 3) * 8;
    const size_t aoff0 = (size_t)(m0 + wave * 16 + srow) * DD + scol;
    const size_t aoff1 = (size_t)(m0 + (wave + 4) * 16 + srow) * DD + scol;
    const size_t boff0 = (size_t)(nl + wave * 16 + srow) * DD + scol;
    const size_t boff1 = (size_t)(nl + (wave + 4) * 16 + srow) * DD + scol;
    ushort_t* lA0 = &As[wave * 16][0];
    ushort_t* lA1 = &As[(wave + 4) * 16][0];
    ushort_t* lB0 = &Bs[wave * 16][0];
    ushort_t* lB1 = &Bs[(wave + 4) * 16][0];

    f32x4 acc[4][4] = {};
    for (int k0 = 0; k0 < DD; k0 += 32) {
        __syncthreads();
        glds16(Xbf + aoff0 + k0, lA0);
        glds16(Xbf + aoff1 + k0, lA1);
        glds16(Bt  + boff0 + k0, lB0);
        glds16(Bt  + boff1 + k0, lB1);
        __syncthreads();
        short8 af[4], bf8[4];
#pragma unroll
        for (int i = 0; i < 4; ++i) af[i]  = *(const short8*)&As[wr * 64 + i * 16 + n16][quad * 8];
#pragma unroll
        for (int j = 0; j < 4; ++j) bf8[j] = *(const short8*)&Bs[wc * 64 + j * 16 + n16][quad * 8];
#pragma unroll
        for (int i = 0; i < 4; ++i)
#pragma unroll
            for (int j = 0; j < 4; ++j)
                acc[i][j] = __builtin_amdgcn_mfma_f32_16x16x32_bf16(af[i], bf8[j], acc[i][j], 0, 0, 0);
    }

    const float QSC = 0.18033688011112042f;   // 0.125 * log2(e)
#pragma unroll
    for (int i = 0; i < 4; ++i) {
#pragma unroll
        for (int r = 0; r < 4; ++r) {
            const int row = m0 + wr * 64 + i * 16 + quad * 4 + r;
            ushort_t* outp = QKVb + (size_t)row * NTOT + n0 + wc * 64 + n16;
            float v0 = acc[i][0][r], v1 = acc[i][1][r];
            float v2 = acc[i][2][r], v3 = acc[i][3][r];
            if (mode < 2) {            // partial RoPE on head dims 0..31
                const int s = row & (SS - 1);
                float c0 = cosb[s * 32 + n16],      s0 = sinb[s * 32 + n16];
                float c1 = cosb[s * 32 + 16 + n16], s1 = sinb[s * 32 + 16 + n16];
                float nr = v0 * c0 - v1 * s0;
                float ni = v1 * c1 + v0 * s1;
                v0 = nr; v1 = ni;
            }
            if (mode == 0) { v0 *= QSC; v1 *= QSC; v2 *= QSC; v3 *= QSC; }
            outp[0]  = f2bf(v0);
            outp[16] = f2bf(v1);
            outp[32] = f2bf(v2);
            outp[48] = f2bf(v3);
        }
    }
}

// ---------------------------------------------------------------------------
// K3: MFMA bf16 flash attention, NO-MAX softmax, 32 q/wave (R4 shape) +
// CROSS-TILE REGISTER PREFETCH: tile kt+1's K/V global loads are issued
// right after the staging barrier, overlapping ~200-900cy global latency
// with tile kt's compute; only the LDS write sits between barriers.
// Block = 256 thr (4 waves) x 128 q x 1 head.  LDS 37.9 KB, VGPR ~80.
// ---------------------------------------------------------------------------
__global__ __launch_bounds__(256) void k_attn(const ushort_t* __restrict__ QKVb,
                                              const ushort_t* __restrict__ VT,
                                              ushort_t* __restrict__ AOb)
{
    __shared__ __align__(16) ushort_t Ks[64][72];
    __shared__ __align__(16) ushort_t Vs[64][72];   // Vs[d][ktok]
    __shared__ __align__(16) ushort_t Ps[128][76];

    const int t    = threadIdx.x;
    const int wave = t >> 6;
    const int quad = (t >> 4) & 3;
    const int n16  = t & 15;
    const int q0   = blockIdx.x * 128;
    const int h    = blockIdx.y;
    const int b    = blockIdx.z;
    const int kh   = h >> 2;

    const int sr = t >> 2;            // 0..63 staging row
    const int sc = (t & 3) * 8;       // K staging col
    const int vc = (t & 3) * 16;      // V staging col

    // loop-invariant Q A-frags from global (pre-scaled by 0.125*log2e)
    short8 qf[2][2];
#pragma unroll
    for (int m = 0; m < 2; ++m)
#pragma unroll
        for (int kc = 0; kc < 2; ++kc)
            qf[m][kc] = *(const short8*)(QKVb +
                (size_t)(b * SS + q0 + wave * 32 + m * 16 + n16) * NTOT +
                h * HD + kc * 32 + quad * 8);

    float l_p[2][4] = {};             // per-lane partial row sums
    f32x4 acc_o[2][4] = {};

    const ushort_t* Kbase = QKVb + (size_t)(b * SS) * NTOT + DD + kh * HD;
    const ushort_t* Vbase = VT + ((size_t)b * KVD + kh * 64) * SS;

    // prefetch tile 0 into registers
    uint4 kp0, kp1, vp0, vp1;
    {
        const ushort_t* Kg = Kbase + (size_t)sr * NTOT + sc;
        kp0 = *(const uint4*)(Kg);
        kp1 = *(const uint4*)(Kg + 32);
        const ushort_t* Vg = Vbase + (size_t)sr * SS + vc;
        vp0 = *(const uint4*)(Vg);
        vp1 = *(const uint4*)(Vg + 8);
    }

    for (int kt = 0; kt < SS / 64; ++kt) {
        __syncthreads();   // prev-tile readers of Ks/Vs done
        *(uint4*)&Ks[sr][sc]      = kp0;
        *(uint4*)&Ks[sr][sc + 32] = kp1;
        *(uint4*)&Vs[sr][vc]      = vp0;
        *(uint4*)&Vs[sr][vc + 8]  = vp1;
        __syncthreads();

        // issue next tile's global loads now; latency hides behind compute
        if (kt + 1 < SS / 64) {
            const int k0n = (kt + 1) * 64;
            const ushort_t* Kg = Kbase + (size_t)(k0n + sr) * NTOT + sc;
            kp0 = *(const uint4*)(Kg);
            kp1 = *(const uint4*)(Kg + 32);
            const ushort_t* Vg = Vbase + (size_t)sr * SS + k0n + vc;
            vp0 = *(const uint4*)(Vg);
            vp1 = *(const uint4*)(Vg + 8);
        }

        // ---- QK^T: S[32q][64k] per wave ----
        f32x4 s_acc[2][4] = {};
#pragma unroll
        for (int kc = 0; kc < 2; ++kc) {
            short8 bf[4];
#pragma unroll
            for (int jj = 0; jj < 4; ++jj)
                bf[jj] = *(const short8*)&Ks[jj * 16 + n16][kc * 32 + quad * 8];
#pragma unroll
            for (int m = 0; m < 2; ++m)
#pragma unroll
                for (int jj = 0; jj < 4; ++jj)
                    s_acc[m][jj] = __builtin_amdgcn_mfma_f32_16x16x32_bf16(
                        qf[m][kc], bf[jj], s_acc[m][jj], 0, 0, 0);
        }

        // ---- p = 2^s; accumulate partial l; P -> wave-private LDS rows ----
#pragma unroll
        for (int m = 0; m < 2; ++m)
#pragma unroll
            for (int r = 0; r < 4; ++r) {
                float p0 = EXP2(s_acc[m][0][r]);
                float p1 = EXP2(s_acc[m][1][r]);
                float p2 = EXP2(s_acc[m][2][r]);
                float p3 = EXP2(s_acc[m][3][r]);
                ushort_t* pr = &Ps[wave * 32 + m * 16 + quad * 4 + r][n16];
                pr[0]  = f2bf_trunc(p0);
                pr[16] = f2bf_trunc(p1);
                pr[32] = f2bf_trunc(p2);
                pr[48] = f2bf_trunc(p3);
                l_p[m][r] += (p0 + p1) + (p2 + p3);
            }

        // ---- PV (Ps rows wave-private; same-wave RAW via lgkmcnt) ----
#pragma unroll
        for (int kc = 0; kc < 2; ++kc) {
            short8 vb[4];
#pragma unroll
            for (int dd = 0; dd < 4; ++dd)
                vb[dd] = *(const short8*)&Vs[dd * 16 + n16][kc * 32 + quad * 8];
#pragma unroll
            for (int m = 0; m < 2; ++m) {
                short8 pa = *(const short8*)&Ps[wave * 32 + m * 16 + n16][kc * 32 + quad * 8];
#pragma unroll
                for (int dd = 0; dd < 4; ++dd)
                    acc_o[m][dd] = __builtin_amdgcn_mfma_f32_16x16x32_bf16(
                        pa, vb[dd], acc_o[m][dd], 0, 0, 0);
            }
        }
    }

    // ---- epilogue: one lane-reduction of l, then O/l ----
#pragma unroll
    for (int m = 0; m < 2; ++m) {
        float inv[4];
#pragma unroll
        for (int r = 0; r < 4; ++r) {
            float s = l_p[m][r];
#pragma unroll
            for (int msk = 1; msk < 16; msk <<= 1)
                s += __shfl_xor(s, msk);
            inv[r] = 1.0f / s;
        }
#pragma unroll
        for (int dd = 0; dd < 4; ++dd)
#pragma unroll
            for (int r = 0; r < 4; ++r) {
                int q = q0 + wave * 32 + m * 16 + quad * 4 + r;
                AOb[(size_t)(b * SS + q) * DD + h * HD + dd * 16 + n16] =
                    f2bf(acc_o[m][dd][r] * inv[r]);
            }
    }
}

// ---------------------------------------------------------------------------
// K4: MFMA out-proj.  out[MM][DD](fp32) = AOb @ Wot^T + bo + HS
// ---------------------------------------------------------------------------
__global__ __launch_bounds__(256) void k_out_mfma(const ushort_t* __restrict__ AOb,
                                                  const ushort_t* __restrict__ Wot,
                                                  const float* __restrict__ bo,
                                                  const float* __restrict__ HS,
                                                  float* __restrict__ out)
{
    __shared__ ushort_t As[128][32];
    __shared__ ushort_t Bs[128][32];
    const int t = threadIdx.x, lane = t & 63, wave = t >> 6;
    const int n16 = lane & 15, quad = lane >> 4;
    const int wr = wave >> 1, wc = wave & 1;
    const int n0 = blockIdx.x * 128;
    const int m0 = blockIdx.y * 128;

    const int srow = lane >> 2;
    const int scol = (lane & 3) * 8;
    const size_t aoff0 = (size_t)(m0 + wave * 16 + srow) * DD + scol;
    const size_t aoff1 = (size_t)(m0 + (wave + 4) * 16 + srow) * DD + scol;
    const size_t boff0 = (size_t)(n0 + wave * 16 + srow) * DD + scol;
    const size_t boff1 = (size_t)(n0 + (wave + 4) * 16 + srow) * DD + scol;
    ushort_t* lA0 = &As[wave * 16][0];
    ushort_t* lA1 = &As[(wave + 4) * 16][0];
    ushort_t* lB0 = &Bs[wave * 16][0];
    ushort_t* lB1 = &Bs[(wave + 4) * 16][0];

    f32x4 acc[4][4] = {};
    for (int k0 = 0; k0 < DD; k0 += 32) {
        __syncthreads();
        glds16(AOb + aoff0 + k0, lA0);
        glds16(AOb + aoff1 + k0, lA1);
        glds16(Wot + boff0 + k0, lB0);
        glds16(Wot + boff1 + k0, lB1);
        __syncthreads();
        short8 af[4], bf8[4];
#pragma unroll
        for (int i = 0; i < 4; ++i) af[i]  = *(const short8*)&As[wr * 64 + i * 16 + n16][quad * 8];
#pragma unroll
        for (int j = 0; j < 4; ++j) bf8[j] = *(const short8*)&Bs[wc * 64 + j * 16 + n16][quad * 8];
#pragma unroll
        for (int i = 0; i < 4; ++i)
#pragma unroll
            for (int j = 0; j < 4; ++j)
                acc[i][j] = __builtin_amdgcn_mfma_f32_16x16x32_bf16(af[i], bf8[j], acc[i][j], 0, 0, 0);
    }

    const int colb = n0 + wc * 64 + n16;
    float bo4[4];
#pragma unroll
    for (int j = 0; j < 4; ++j) bo4[j] = bo[colb + j * 16];
#pragma unroll
    for (int i = 0; i < 4; ++i) {
#pragma unroll
        for (int r = 0; r < 4; ++r) {
            const int row = m0 + wr * 64 + i * 16 + quad * 4 + r;
            float* op = out + (size_t)row * DD + colb;
            const float* hp = HS + (size_t)row * DD + colb;
#pragma unroll
            for (int j = 0; j < 4; ++j)
                op[j * 16] = acc[i][j][r] + bo4[j] + hp[j * 16];
        }
    }
}

extern "C" void kernel_launch(void* const* d_in, const int* in_sizes, int n_in,
                              void* d_out, int out_size, void* d_ws, size_t ws_size,
                              hipStream_t stream)
{
    const float* HS   = (const float*)d_in[0];
    const float* cosb = (const float*)d_in[1];
    const float* sinb = (const float*)d_in[2];
    const float* Wq   = (const float*)d_in[3];
    const float* Wk   = (const float*)d_in[4];
    const float* Wv   = (const float*)d_in[5];
    const float* Wo   = (const float*)d_in[6];
    const float* bo   = (const float*)d_in[7];
    float* out = (float*)d_out;

    ushort_t* Xbf  = (ushort_t*)d_ws;                  // [MM][DD]
    ushort_t* QKVb = Xbf  + (size_t)MM * DD;           // [MM][NTOT]
    ushort_t* AOb  = QKVb + (size_t)MM * NTOT;         // [MM][DD]
    ushort_t* Wqt  = AOb  + (size_t)MM * DD;           // [DD][DD]
    ushort_t* Wkt  = Wqt  + (size_t)DD * DD;           // [KVD][DD]
    ushort_t* Wvt  = Wkt  + (size_t)KVD * DD;          // [KVD][DD]
    ushort_t* Wot  = Wvt  + (size_t)KVD * DD;          // [DD][DD]
    ushort_t* VT   = Wot  + (size_t)DD * DD;           // [BB][KVD][SS]

    const int nprep = NCVT + 2304 + 576 + 576 + 2304;
    k_prep    <<<dim3(nprep), 256, 0, stream>>>(HS, Wq, Wk, Wv, Wo,
                                                Xbf, Wqt, Wkt, Wvt, Wot);
    k_qkv_mfma<<<dim3(NTOT / 128, MM / 128), 256, 0, stream>>>(Xbf, Wqt, Wkt, Wvt, cosb, sinb, QKVb);
    k_vt      <<<dim3(SS / 32, KVD / 32, BB), 256, 0, stream>>>(QKVb, VT);
    k_attn    <<<dim3(SS / 128, HEADS, BB),   256, 0, stream>>>(QKVb, VT, AOb);
    k_out_mfma<<<dim3(DD / 128, MM / 128),    256, 0, stream>>>(AOb, Wot, bo, HS, out);
}

// Round 8
// 288.219 us; speedup vs baseline: 1.2102x; 1.0722x over previous
//
#include <hip/hip_runtime.h>

#define HEADS 24
#define KVH   6
#define HD    64
#define BB    2
#define SS    2048
#define DD    1536
#define KVD   384      // KVH*HD
#define QKD   1920     // DD + KVD (Q|K only; V lives in VT)
#define MM    4096     // BB*SS

typedef unsigned short ushort_t;
typedef __attribute__((ext_vector_type(8))) short short8;
typedef __attribute__((ext_vector_type(4))) float f32x4;

__device__ __forceinline__ ushort_t f2bf(float f) {
    union { float f; unsigned u; } v; v.f = f;
    return (ushort_t)((v.u + 0x8000u) >> 16);
}
__device__ __forceinline__ ushort_t f2bf_trunc(float f) {
    union { float f; unsigned u; } v; v.f = f;
    return (ushort_t)(v.u >> 16);
}
__device__ __forceinline__ unsigned pk2(float a, float b) {
    union { float f; unsigned u; } x, y; x.f = a; y.f = b;
    return ((x.u + 0x8000u) >> 16) | (((y.u + 0x8000u) >> 16) << 16);
}
#if __has_builtin(__builtin_amdgcn_exp2f)
#define EXP2(x) __builtin_amdgcn_exp2f(x)
#else
#define EXP2(x) exp2f(x)
#endif
// async global->LDS, 16B per lane; lds ptr must be wave-uniform base.
__device__ __forceinline__ void glds16(const void* g, void* l) {
    __builtin_amdgcn_global_load_lds(
        (const __attribute__((address_space(1))) void*)g,
        (__attribute__((address_space(3))) void*)l, 16, 0, 0);
}

// ---------------------------------------------------------------------------
// K0: fused preprocessing — cvt X + 4x weight transpose-convert.
// ---------------------------------------------------------------------------
__device__ __forceinline__ void tconv_body(const float* __restrict__ in,
                                           ushort_t* __restrict__ out,
                                           int R, int C, int cb, int rb)
{
    __shared__ ushort_t tile[32][33];
    const int tx = threadIdx.x & 31, ty = threadIdx.x >> 5;
    const int c0 = cb * 32, r0 = rb * 32;
#pragma unroll
    for (int i = 0; i < 4; ++i)
        tile[ty + i * 8][tx] = f2bf(in[(size_t)(r0 + ty + i * 8) * C + c0 + tx]);
    __syncthreads();
#pragma unroll
    for (int i = 0; i < 4; ++i)
        out[(size_t)(c0 + ty + i * 8) * R + r0 + tx] = tile[tx][ty + i * 8];
}

#define NCVT (MM * DD / 4 / 256)     // 6144
__global__ __launch_bounds__(256) void k_prep(const float* __restrict__ HS,
                                              const float* __restrict__ Wq,
                                              const float* __restrict__ Wk,
                                              const float* __restrict__ Wv,
                                              const float* __restrict__ Wo,
                                              ushort_t* __restrict__ Xbf,
                                              ushort_t* __restrict__ Wqt,
                                              ushort_t* __restrict__ Wkt,
                                              ushort_t* __restrict__ Wvt,
                                              ushort_t* __restrict__ Wot)
{
    int bid = blockIdx.x;
    if (bid < NCVT) {
        int i = bid * 256 + threadIdx.x;
        float4 v = ((const float4*)HS)[i];
        uint2 o = { pk2(v.x, v.y), pk2(v.z, v.w) };
        ((uint2*)Xbf)[i] = o;
        return;
    }
    bid -= NCVT;
    if (bid < 2304) { tconv_body(Wq, Wqt, DD, DD,  bid % 48, bid / 48); return; }
    bid -= 2304;
    if (bid < 576)  { tconv_body(Wk, Wkt, DD, KVD, bid % 12, bid / 12); return; }
    bid -= 576;
    if (bid < 576)  { tconv_body(Wv, Wvt, DD, KVD, bid % 12, bid / 12); return; }
    bid -= 576;
    tconv_body(Wo, Wot, DD, DD, bid % 48, bid / 48);
}

// ---------------------------------------------------------------------------
// K1: MFMA Q|K projection + fused partial RoPE + fused Q-scale.
// C[MM][QKD](bf16) = Xbf @ [Wqt|Wkt]^T.  128x128 tiles, grid 15x32 = 480.
// Q scale = (1/8)*log2(e) so attention can use 2^s = e^(q.k/8) directly.
// ---------------------------------------------------------------------------
__global__ __launch_bounds__(256) void k_qkv_mfma(const ushort_t* __restrict__ Xbf,
                                                  const ushort_t* __restrict__ Wqt,
                                                  const ushort_t* __restrict__ Wkt,
                                                  const float* __restrict__ cosb,
                                                  const float* __restrict__ sinb,
                                                  ushort_t* __restrict__ QKVb)
{
    __shared__ ushort_t As[128][32];
    __shared__ ushort_t Bs[128][32];
    const int t = threadIdx.x, lane = t & 63, wave = t >> 6;
    const int n16 = lane & 15, quad = lane >> 4;
    const int wr = wave >> 1, wc = wave & 1;
    const int nt = blockIdx.x;
    const int n0 = nt * 128;
    const int m0 = blockIdx.y * 128;
    const ushort_t* Bt; int nl, isq;
    if (nt < 12) { Bt = Wqt; nl = n0;      isq = 1; }
    else         { Bt = Wkt; nl = n0 - DD; isq = 0; }

    const int srow = lane >> 2;
    const int scol = (lane & 3) * 8;
    const size_t aoff0 = (size_t)(m0 + wave * 16 + srow) * DD + scol;
    const size_t aoff1 = (size_t)(m0 + (wave + 4) * 16 + srow) * DD + scol;
    const size_t boff0 = (size_t)(nl + wave * 16 + srow) * DD + scol;
    const size_t boff1 = (size_t)(nl + (wave + 4) * 16 + srow) * DD + scol;
    ushort_t* lA0 = &As[wave * 16][0];
    ushort_t* lA1 = &As[(wave + 4) * 16][0];
    ushort_t* lB0 = &Bs[wave * 16][0];
    ushort_t* lB1 = &Bs[(wave + 4) * 16][0];

    f32x4 acc[4][4] = {};
    for (int k0 = 0; k0 < DD; k0 += 32) {
        __syncthreads();
        glds16(Xbf + aoff0 + k0, lA0);
        glds16(Xbf + aoff1 + k0, lA1);
        glds16(Bt  + boff0 + k0, lB0);
        glds16(Bt  + boff1 + k0, lB1);
        __syncthreads();
        short8 af[4], bf8[4];
#pragma unroll
        for (int i = 0; i < 4; ++i) af[i]  = *(const short8*)&As[wr * 64 + i * 16 + n16][quad * 8];
#pragma unroll
        for (int j = 0; j < 4; ++j) bf8[j] = *(const short8*)&Bs[wc * 64 + j * 16 + n16][quad * 8];
#pragma unroll
        for (int i = 0; i < 4; ++i)
#pragma unroll
            for (int j = 0; j < 4; ++j)
                acc[i][j] = __builtin_amdgcn_mfma_f32_16x16x32_bf16(af[i], bf8[j], acc[i][j], 0, 0, 0);
    }

    const float QSC = 0.18033688011112042f;   // 0.125 * log2(e)
#pragma unroll
    for (int i = 0; i < 4; ++i) {
#pragma unroll
        for (int r = 0; r < 4; ++r) {
            const int row = m0 + wr * 64 + i * 16 + quad * 4 + r;
            ushort_t* outp = QKVb + (size_t)row * QKD + n0 + wc * 64 + n16;
            float v0 = acc[i][0][r], v1 = acc[i][1][r];
            float v2 = acc[i][2][r], v3 = acc[i][3][r];
            {   // partial RoPE on head dims 0..31 (applies to both Q and K)
                const int s = row & (SS - 1);
                float c0 = cosb[s * 32 + n16],      s0 = sinb[s * 32 + n16];
                float c1 = cosb[s * 32 + 16 + n16], s1 = sinb[s * 32 + 16 + n16];
                float nr = v0 * c0 - v1 * s0;
                float ni = v1 * c1 + v0 * s1;
                v0 = nr; v1 = ni;
            }
            if (isq) { v0 *= QSC; v1 *= QSC; v2 *= QSC; v3 *= QSC; }
            outp[0]  = f2bf(v0);
            outp[16] = f2bf(v1);
            outp[32] = f2bf(v2);
            outp[48] = f2bf(v3);
        }
    }
}

// ---------------------------------------------------------------------------
// K2: V^T as a GEMM.  VT[c][tok] = sum_k WvT[c][k] * Xbf[tok][k].
// 64m x 128n tiles, grid (MM/128=32) x (KVD/64=6) = 192 blocks.
// Epilogue writes VT[b][c][s] coalesced along tokens — replaces k_vt.
// ---------------------------------------------------------------------------
__global__ __launch_bounds__(256) void k_vtg(const ushort_t* __restrict__ Wvt,
                                             const ushort_t* __restrict__ Xbf,
                                             ushort_t* __restrict__ VT)
{
    __shared__ ushort_t As[64][32];    // WvT rows (c)
    __shared__ ushort_t Bs[128][32];   // Xbf rows (tok)
    const int t = threadIdx.x, lane = t & 63, wave = t >> 6;
    const int n16 = lane & 15, quad = lane >> 4;
    const int wr = wave >> 1, wc = wave & 1;
    const int n0 = blockIdx.x * 128;   // tokens
    const int m0 = blockIdx.y * 64;    // channels c

    const int srow = lane >> 2;
    const int scol = (lane & 3) * 8;
    const size_t aoff  = (size_t)(m0 + wave * 16 + srow) * DD + scol;
    const size_t boff0 = (size_t)(n0 + wave * 32 + srow) * DD + scol;
    const size_t boff1 = boff0 + (size_t)16 * DD;
    ushort_t* lA  = &As[wave * 16][0];
    ushort_t* lB0 = &Bs[wave * 32][0];
    ushort_t* lB1 = &Bs[wave * 32 + 16][0];

    f32x4 acc[2][4] = {};
    for (int k0 = 0; k0 < DD; k0 += 32) {
        __syncthreads();
        glds16(Wvt + aoff  + k0, lA);
        glds16(Xbf + boff0 + k0, lB0);
        glds16(Xbf + boff1 + k0, lB1);
        __syncthreads();
        short8 af[2], bf8[4];
#pragma unroll
        for (int i = 0; i < 2; ++i) af[i]  = *(const short8*)&As[wr * 32 + i * 16 + n16][quad * 8];
#pragma unroll
        for (int j = 0; j < 4; ++j) bf8[j] = *(const short8*)&Bs[wc * 64 + j * 16 + n16][quad * 8];
#pragma unroll
        for (int i = 0; i < 2; ++i)
#pragma unroll
            for (int j = 0; j < 4; ++j)
                acc[i][j] = __builtin_amdgcn_mfma_f32_16x16x32_bf16(af[i], bf8[j], acc[i][j], 0, 0, 0);
    }

    const int b = n0 >> 11;            // tokens tile never straddles batch
#pragma unroll
    for (int i = 0; i < 2; ++i)
#pragma unroll
        for (int r = 0; r < 4; ++r) {
            const int c = m0 + wr * 32 + i * 16 + quad * 4 + r;
            ushort_t* op = VT + ((size_t)b * KVD + c) * SS + (n0 & (SS - 1)) + wc * 64 + n16;
#pragma unroll
            for (int j = 0; j < 4; ++j)
                op[j * 16] = f2bf(acc[i][j][r]);
        }
}

// ---------------------------------------------------------------------------
// K3: MFMA bf16 flash attention (R4 shape), NO-MAX softmax, 32 q/wave.
// Block = 256 thr x 128 q x 1 head; K [ktok][d] from QKVb (stride QKD),
// V [d][ktok] from VT; P stride 76.  LDS 37.9 KB, VGPR ~64.
// ---------------------------------------------------------------------------
__global__ __launch_bounds__(256) void k_attn(const ushort_t* __restrict__ QKVb,
                                              const ushort_t* __restrict__ VT,
                                              ushort_t* __restrict__ AOb)
{
    __shared__ __align__(16) ushort_t Ks[64][72];
    __shared__ __align__(16) ushort_t Vs[64][72];   // Vs[d][ktok]
    __shared__ __align__(16) ushort_t Ps[128][76];

    const int t    = threadIdx.x;
    const int wave = t >> 6;
    const int quad = (t >> 4) & 3;
    const int n16  = t & 15;
    const int q0   = blockIdx.x * 128;
    const int h    = blockIdx.y;
    const int b    = blockIdx.z;
    const int kh   = h >> 2;

    const int sr = t >> 2;            // 0..63 staging row
    const int sc = (t & 3) * 8;       // K staging col
    const int vc = (t & 3) * 16;      // V staging col

    // loop-invariant Q A-frags from global (pre-scaled by 0.125*log2e)
    short8 qf[2][2];
#pragma unroll
    for (int m = 0; m < 2; ++m)
#pragma unroll
        for (int kc = 0; kc < 2; ++kc)
            qf[m][kc] = *(const short8*)(QKVb +
                (size_t)(b * SS + q0 + wave * 32 + m * 16 + n16) * QKD +
                h * HD + kc * 32 + quad * 8);

    float l_p[2][4] = {};             // per-lane partial row sums
    f32x4 acc_o[2][4] = {};

    const ushort_t* Kbase = QKVb + (size_t)(b * SS) * QKD + DD + kh * HD;
    const ushort_t* Vbase = VT + ((size_t)b * KVD + kh * 64) * SS;

    for (int kt = 0; kt < SS / 64; ++kt) {
        const int k0 = kt * 64;
        __syncthreads();   // prev-tile readers of Ks/Vs done
        {
            const ushort_t* Kg = Kbase + (size_t)(k0 + sr) * QKD + sc;
            *(uint4*)&Ks[sr][sc]      = *(const uint4*)(Kg);
            *(uint4*)&Ks[sr][sc + 32] = *(const uint4*)(Kg + 32);
            const ushort_t* Vg = Vbase + (size_t)sr * SS + k0 + vc;
            *(uint4*)&Vs[sr][vc]      = *(const uint4*)(Vg);
            *(uint4*)&Vs[sr][vc + 8]  = *(const uint4*)(Vg + 8);
        }
        __syncthreads();

        // ---- QK^T: S[32q][64k] per wave ----
        f32x4 s_acc[2][4] = {};
#pragma unroll
        for (int kc = 0; kc < 2; ++kc) {
            short8 bf[4];
#pragma unroll
            for (int jj = 0; jj < 4; ++jj)
                bf[jj] = *(const short8*)&Ks[jj * 16 + n16][kc * 32 + quad * 8];
#pragma unroll
            for (int m = 0; m < 2; ++m)
#pragma unroll
                for (int jj = 0; jj < 4; ++jj)
                    s_acc[m][jj] = __builtin_amdgcn_mfma_f32_16x16x32_bf16(
                        qf[m][kc], bf[jj], s_acc[m][jj], 0, 0, 0);
        }

        // ---- p = 2^s; accumulate partial l; P -> wave-private LDS rows ----
#pragma unroll
        for (int m = 0; m < 2; ++m)
#pragma unroll
            for (int r = 0; r < 4; ++r) {
                float p0 = EXP2(s_acc[m][0][r]);
                float p1 = EXP2(s_acc[m][1][r]);
                float p2 = EXP2(s_acc[m][2][r]);
                float p3 = EXP2(s_acc[m][3][r]);
                ushort_t* pr = &Ps[wave * 32 + m * 16 + quad * 4 + r][n16];
                pr[0]  = f2bf_trunc(p0);
                pr[16] = f2bf_trunc(p1);
                pr[32] = f2bf_trunc(p2);
                pr[48] = f2bf_trunc(p3);
                l_p[m][r] += (p0 + p1) + (p2 + p3);
            }

        // ---- PV (Ps rows wave-private; same-wave RAW via lgkmcnt) ----
#pragma unroll
        for (int kc = 0; kc < 2; ++kc) {
            short8 vb[4];
#pragma unroll
            for (int dd = 0; dd < 4; ++dd)
                vb[dd] = *(const short8*)&Vs[dd * 16 + n16][kc * 32 + quad * 8];
#pragma unroll
            for (int m = 0; m < 2; ++m) {
                short8 pa = *(const short8*)&Ps[wave * 32 + m * 16 + n16][kc * 32 + quad * 8];
#pragma unroll
                for (int dd = 0; dd < 4; ++dd)
                    acc_o[m][dd] = __builtin_amdgcn_mfma_f32_16x16x32_bf16(
                        pa, vb[dd], acc_o[m][dd], 0, 0, 0);
            }
        }
    }

    // ---- epilogue: one lane-reduction of l, then O/l ----
#pragma unroll
    for (int m = 0; m < 2; ++m) {
        float inv[4];
#pragma unroll
        for (int r = 0; r < 4; ++r) {
            float s = l_p[m][r];
#pragma unroll
            for (int msk = 1; msk < 16; msk <<= 1)
                s += __shfl_xor(s, msk);
            inv[r] = 1.0f / s;
        }
#pragma unroll
        for (int dd = 0; dd < 4; ++dd)
#pragma unroll
            for (int r = 0; r < 4; ++r) {
                int q = q0 + wave * 32 + m * 16 + quad * 4 + r;
                AOb[(size_t)(b * SS + q) * DD + h * HD + dd * 16 + n16] =
                    f2bf(acc_o[m][dd][r] * inv[r]);
            }
    }
}

// ---------------------------------------------------------------------------
// K4: MFMA out-proj.  out[MM][DD](fp32) = AOb @ Wot^T + bo + HS.
// 64m x 128n tiles, grid (DD/128=12) x (MM/64=64) = 768 = exactly 3/CU.
// ---------------------------------------------------------------------------
__global__ __launch_bounds__(256) void k_out_mfma(const ushort_t* __restrict__ AOb,
                                                  const ushort_t* __restrict__ Wot,
                                                  const float* __restrict__ bo,
                                                  const float* __restrict__ HS,
                                                  float* __restrict__ out)
{
    __shared__ ushort_t As[64][32];    // AOb rows (m)
    __shared__ ushort_t Bs[128][32];   // Wot rows (n)
    const int t = threadIdx.x, lane = t & 63, wave = t >> 6;
    const int n16 = lane & 15, quad = lane >> 4;
    const int wr = wave >> 1, wc = wave & 1;
    const int n0 = blockIdx.x * 128;
    const int m0 = blockIdx.y * 64;

    const int srow = lane >> 2;
    const int scol = (lane & 3) * 8;
    const size_t aoff  = (size_t)(m0 + wave * 16 + srow) * DD + scol;
    const size_t boff0 = (size_t)(n0 + wave * 32 + srow) * DD + scol;
    const size_t boff1 = boff0 + (size_t)16 * DD;
    ushort_t* lA  = &As[wave * 16][0];
    ushort_t* lB0 = &Bs[wave * 32][0];
    ushort_t* lB1 = &Bs[wave * 32 + 16][0];

    f32x4 acc[2][4] = {};
    for (int k0 = 0; k0 < DD; k0 += 32) {
        __syncthreads();
        glds16(AOb + aoff  + k0, lA);
        glds16(Wot + boff0 + k0, lB0);
        glds16(Wot + boff1 + k0, lB1);
        __syncthreads();
        short8 af[2], bf8[4];
#pragma unroll
        for (int i = 0; i < 2; ++i) af[i]  = *(const short8*)&As[wr * 32 + i * 16 + n16][quad * 8];
#pragma unroll
        for (int j = 0; j < 4; ++j) bf8[j] = *(const short8*)&Bs[wc * 64 + j * 16 + n16][quad * 8];
#pragma unroll
        for (int i = 0; i < 2; ++i)
#pragma unroll
            for (int j = 0; j < 4; ++j)
                acc[i][j] = __builtin_amdgcn_mfma_f32_16x16x32_bf16(af[i], bf8[j], acc[i][j], 0, 0, 0);
    }

    const int colb = n0 + wc * 64 + n16;
    float bo4[4];
#pragma unroll
    for (int j = 0; j < 4; ++j) bo4[j] = bo[colb + j * 16];
#pragma unroll
    for (int i = 0; i < 2; ++i) {
#pragma unroll
        for (int r = 0; r < 4; ++r) {
            const int row = m0 + wr * 32 + i * 16 + quad * 4 + r;
            float* op = out + (size_t)row * DD + colb;
            const float* hp = HS + (size_t)row * DD + colb;
#pragma unroll
            for (int j = 0; j < 4; ++j)
                op[j * 16] = acc[i][j][r] + bo4[j] + hp[j * 16];
        }
    }
}

extern "C" void kernel_launch(void* const* d_in, const int* in_sizes, int n_in,
                              void* d_out, int out_size, void* d_ws, size_t ws_size,
                              hipStream_t stream)
{
    const float* HS   = (const float*)d_in[0];
    const float* cosb = (const float*)d_in[1];
    const float* sinb = (const float*)d_in[2];
    const float* Wq   = (const float*)d_in[3];
    const float* Wk   = (const float*)d_in[4];
    const float* Wv   = (const float*)d_in[5];
    const float* Wo   = (const float*)d_in[6];
    const float* bo   = (const float*)d_in[7];
    float* out = (float*)d_out;

    ushort_t* Xbf  = (ushort_t*)d_ws;                  // [MM][DD]
    ushort_t* QKVb = Xbf  + (size_t)MM * DD;           // [MM][QKD]
    ushort_t* AOb  = QKVb + (size_t)MM * QKD;          // [MM][DD]
    ushort_t* Wqt  = AOb  + (size_t)MM * DD;           // [DD][DD]
    ushort_t* Wkt  = Wqt  + (size_t)DD * DD;           // [KVD][DD]
    ushort_t* Wvt  = Wkt  + (size_t)KVD * DD;          // [KVD][DD]
    ushort_t* Wot  = Wvt  + (size_t)KVD * DD;          // [DD][DD]
    ushort_t* VT   = Wot  + (size_t)DD * DD;           // [BB][KVD][SS]

    const int nprep = NCVT + 2304 + 576 + 576 + 2304;
    k_prep    <<<dim3(nprep), 256, 0, stream>>>(HS, Wq, Wk, Wv, Wo,
                                                Xbf, Wqt, Wkt, Wvt, Wot);
    k_qkv_mfma<<<dim3(QKD / 128, MM / 128), 256, 0, stream>>>(Xbf, Wqt, Wkt, cosb, sinb, QKVb);
    k_vtg     <<<dim3(MM / 128, KVD / 64),  256, 0, stream>>>(Wvt, Xbf, VT);
    k_attn    <<<dim3(SS / 128, HEADS, BB), 256, 0, stream>>>(QKVb, VT, AOb);
    k_out_mfma<<<dim3(DD / 128, MM / 64),   256, 0, stream>>>(AOb, Wot, bo, HS, out);
}

// Round 9
// 270.338 us; speedup vs baseline: 1.2903x; 1.0661x over previous
//
#include <hip/hip_runtime.h>

#define HEADS 24
#define KVH   6
#define HD    64
#define BB    2
#define SS    2048
#define DD    1536
#define KVD   384      // KVH*HD
#define QKD   1920     // DD + KVD (Q|K only; V lives in VT)
#define MM    4096     // BB*SS

typedef unsigned short ushort_t;
typedef __attribute__((ext_vector_type(8))) short short8;
typedef __attribute__((ext_vector_type(4))) short short4v;
typedef __attribute__((ext_vector_type(4))) float f32x4;

__device__ __forceinline__ ushort_t f2bf(float f) {
    union { float f; unsigned u; } v; v.f = f;
    return (ushort_t)((v.u + 0x8000u) >> 16);
}
__device__ __forceinline__ ushort_t f2bf_trunc(float f) {
    union { float f; unsigned u; } v; v.f = f;
    return (ushort_t)(v.u >> 16);
}
__device__ __forceinline__ unsigned pk2(float a, float b) {
    union { float f; unsigned u; } x, y; x.f = a; y.f = b;
    return ((x.u + 0x8000u) >> 16) | (((y.u + 0x8000u) >> 16) << 16);
}
#if __has_builtin(__builtin_amdgcn_exp2f)
#define EXP2(x) __builtin_amdgcn_exp2f(x)
#else
#define EXP2(x) exp2f(x)
#endif
// 16B frag read from an 8B-aligned LDS row (pitch 76): two b64 halves.
__device__ __forceinline__ short8 lds_frag8(const ushort_t* p) {
    short4v lo = *(const short4v*)p;
    short4v hi = *(const short4v*)(p + 4);
    return __builtin_shufflevector(lo, hi, 0, 1, 2, 3, 4, 5, 6, 7);
}
// async global->LDS, 16B per lane; lds ptr must be wave-uniform base.
__device__ __forceinline__ void glds16(const void* g, void* l) {
    __builtin_amdgcn_global_load_lds(
        (const __attribute__((address_space(1))) void*)g,
        (__attribute__((address_space(3))) void*)l, 16, 0, 0);
}

// ---------------------------------------------------------------------------
// K0: fused preprocessing — cvt X + 4x weight transpose-convert.
// ---------------------------------------------------------------------------
__device__ __forceinline__ void tconv_body(const float* __restrict__ in,
                                           ushort_t* __restrict__ out,
                                           int R, int C, int cb, int rb)
{
    __shared__ ushort_t tile[32][33];
    const int tx = threadIdx.x & 31, ty = threadIdx.x >> 5;
    const int c0 = cb * 32, r0 = rb * 32;
#pragma unroll
    for (int i = 0; i < 4; ++i)
        tile[ty + i * 8][tx] = f2bf(in[(size_t)(r0 + ty + i * 8) * C + c0 + tx]);
    __syncthreads();
#pragma unroll
    for (int i = 0; i < 4; ++i)
        out[(size_t)(c0 + ty + i * 8) * R + r0 + tx] = tile[tx][ty + i * 8];
}

#define NCVT (MM * DD / 4 / 256)     // 6144
__global__ __launch_bounds__(256) void k_prep(const float* __restrict__ HS,
                                              const float* __restrict__ Wq,
                                              const float* __restrict__ Wk,
                                              const float* __restrict__ Wv,
                                              const float* __restrict__ Wo,
                                              ushort_t* __restrict__ Xbf,
                                              ushort_t* __restrict__ Wqt,
                                              ushort_t* __restrict__ Wkt,
                                              ushort_t* __restrict__ Wvt,
                                              ushort_t* __restrict__ Wot)
{
    int bid = blockIdx.x;
    if (bid < NCVT) {
        int i = bid * 256 + threadIdx.x;
        float4 v = ((const float4*)HS)[i];
        uint2 o = { pk2(v.x, v.y), pk2(v.z, v.w) };
        ((uint2*)Xbf)[i] = o;
        return;
    }
    bid -= NCVT;
    if (bid < 2304) { tconv_body(Wq, Wqt, DD, DD,  bid % 48, bid / 48); return; }
    bid -= 2304;
    if (bid < 576)  { tconv_body(Wk, Wkt, DD, KVD, bid % 12, bid / 12); return; }
    bid -= 576;
    if (bid < 576)  { tconv_body(Wv, Wvt, DD, KVD, bid % 12, bid / 12); return; }
    bid -= 576;
    tconv_body(Wo, Wot, DD, DD, bid % 48, bid / 48);
}

// ---------------------------------------------------------------------------
// K1: fused projection dispatch.
//   bid <  480 : Q|K projection, 128x128 tiles + RoPE + Q-scale
//   bid >= 480 : V^T GEMM (VT[c][tok] = WvT @ X^T), 64x128 tiles (tail-last)
// ---------------------------------------------------------------------------
__global__ __launch_bounds__(256) void k_proj(const ushort_t* __restrict__ Xbf,
                                              const ushort_t* __restrict__ Wqt,
                                              const ushort_t* __restrict__ Wkt,
                                              const ushort_t* __restrict__ Wvt,
                                              const float* __restrict__ cosb,
                                              const float* __restrict__ sinb,
                                              ushort_t* __restrict__ QKVb,
                                              ushort_t* __restrict__ VT)
{
    __shared__ ushort_t As[128][32];
    __shared__ ushort_t Bs[128][32];
    const int t = threadIdx.x, lane = t & 63, wave = t >> 6;
    const int n16 = lane & 15, quad = lane >> 4;
    const int wr = wave >> 1, wc = wave & 1;
    const int srow = lane >> 2;
    const int scol = (lane & 3) * 8;

    if (blockIdx.x < 480) {
        // ---------------- Q|K projection ----------------
        const int nt = blockIdx.x % 15;
        const int n0 = nt * 128;
        const int m0 = (blockIdx.x / 15) * 128;
        const ushort_t* Bt; int nl, isq;
        if (nt < 12) { Bt = Wqt; nl = n0;      isq = 1; }
        else         { Bt = Wkt; nl = n0 - DD; isq = 0; }

        const size_t aoff0 = (size_t)(m0 + wave * 16 + srow) * DD + scol;
        const size_t aoff1 = (size_t)(m0 + (wave + 4) * 16 + srow) * DD + scol;
        const size_t boff0 = (size_t)(nl + wave * 16 + srow) * DD + scol;
        const size_t boff1 = (size_t)(nl + (wave + 4) * 16 + srow) * DD + scol;
        ushort_t* lA0 = &As[wave * 16][0];
        ushort_t* lA1 = &As[(wave + 4) * 16][0];
        ushort_t* lB0 = &Bs[wave * 16][0];
        ushort_t* lB1 = &Bs[(wave + 4) * 16][0];

        f32x4 acc[4][4] = {};
        for (int k0 = 0; k0 < DD; k0 += 32) {
            __syncthreads();
            glds16(Xbf + aoff0 + k0, lA0);
            glds16(Xbf + aoff1 + k0, lA1);
            glds16(Bt  + boff0 + k0, lB0);
            glds16(Bt  + boff1 + k0, lB1);
            __syncthreads();
            short8 af[4], bf8[4];
#pragma unroll
            for (int i = 0; i < 4; ++i) af[i]  = *(const short8*)&As[wr * 64 + i * 16 + n16][quad * 8];
#pragma unroll
            for (int j = 0; j < 4; ++j) bf8[j] = *(const short8*)&Bs[wc * 64 + j * 16 + n16][quad * 8];
#pragma unroll
            for (int i = 0; i < 4; ++i)
#pragma unroll
                for (int j = 0; j < 4; ++j)
                    acc[i][j] = __builtin_amdgcn_mfma_f32_16x16x32_bf16(af[i], bf8[j], acc[i][j], 0, 0, 0);
        }

        const float QSC = 0.18033688011112042f;   // 0.125 * log2(e)
#pragma unroll
        for (int i = 0; i < 4; ++i) {
#pragma unroll
            for (int r = 0; r < 4; ++r) {
                const int row = m0 + wr * 64 + i * 16 + quad * 4 + r;
                ushort_t* outp = QKVb + (size_t)row * QKD + n0 + wc * 64 + n16;
                float v0 = acc[i][0][r], v1 = acc[i][1][r];
                float v2 = acc[i][2][r], v3 = acc[i][3][r];
                {   // partial RoPE on head dims 0..31 (Q and K)
                    const int s = row & (SS - 1);
                    float c0 = cosb[s * 32 + n16],      s0 = sinb[s * 32 + n16];
                    float c1 = cosb[s * 32 + 16 + n16], s1 = sinb[s * 32 + 16 + n16];
                    float nr = v0 * c0 - v1 * s0;
                    float ni = v1 * c1 + v0 * s1;
                    v0 = nr; v1 = ni;
                }
                if (isq) { v0 *= QSC; v1 *= QSC; v2 *= QSC; v3 *= QSC; }
                outp[0]  = f2bf(v0);
                outp[16] = f2bf(v1);
                outp[32] = f2bf(v2);
                outp[48] = f2bf(v3);
            }
        }
    } else {
        // ---------------- V^T GEMM ----------------
        const int vb = blockIdx.x - 480;
        const int n0 = (vb & 31) * 128;    // tokens
        const int m0 = (vb >> 5) * 64;     // channels c

        const size_t aoff  = (size_t)(m0 + wave * 16 + srow) * DD + scol;
        const size_t boff0 = (size_t)(n0 + wave * 32 + srow) * DD + scol;
        const size_t boff1 = boff0 + (size_t)16 * DD;
        ushort_t* lA  = &As[wave * 16][0];
        ushort_t* lB0 = &Bs[wave * 32][0];
        ushort_t* lB1 = &Bs[wave * 32 + 16][0];

        f32x4 acc[2][4] = {};
        for (int k0 = 0; k0 < DD; k0 += 32) {
            __syncthreads();
            glds16(Wvt + aoff  + k0, lA);
            glds16(Xbf + boff0 + k0, lB0);
            glds16(Xbf + boff1 + k0, lB1);
            __syncthreads();
            short8 af[2], bf8[4];
#pragma unroll
            for (int i = 0; i < 2; ++i) af[i]  = *(const short8*)&As[wr * 32 + i * 16 + n16][quad * 8];
#pragma unroll
            for (int j = 0; j < 4; ++j) bf8[j] = *(const short8*)&Bs[wc * 64 + j * 16 + n16][quad * 8];
#pragma unroll
            for (int i = 0; i < 2; ++i)
#pragma unroll
                for (int j = 0; j < 4; ++j)
                    acc[i][j] = __builtin_amdgcn_mfma_f32_16x16x32_bf16(af[i], bf8[j], acc[i][j], 0, 0, 0);
        }

        const int b = n0 >> 11;            // token tile never straddles batch
#pragma unroll
        for (int i = 0; i < 2; ++i)
#pragma unroll
            for (int r = 0; r < 4; ++r) {
                const int c = m0 + wr * 32 + i * 16 + quad * 4 + r;
                ushort_t* op = VT + ((size_t)b * KVD + c) * SS + (n0 & (SS - 1)) + wc * 64 + n16;
#pragma unroll
                for (int j = 0; j < 4; ++j)
                    op[j * 16] = f2bf(acc[i][j][r]);
            }
    }
}

// ---------------------------------------------------------------------------
// K3: MFMA bf16 flash attention, NO-MAX softmax, 32 q/wave.
// LDS pitch 76 elems (38 dw): frag reads & P traffic <=2-way (free);
// rows 8B-aligned -> b64 staging writes + b64-pair frag reads.
// Block = 256 thr x 128 q x 1 head.  LDS 38.0 KB, VGPR ~64.
// ---------------------------------------------------------------------------
__global__ __launch_bounds__(256) void k_attn(const ushort_t* __restrict__ QKVb,
                                              const ushort_t* __restrict__ VT,
                                              ushort_t* __restrict__ AOb)
{
    __shared__ __align__(16) ushort_t Ks[64][76];
    __shared__ __align__(16) ushort_t Vs[64][76];   // Vs[d][ktok]
    __shared__ __align__(16) ushort_t Ps[128][76];

    const int t    = threadIdx.x;
    const int wave = t >> 6;
    const int quad = (t >> 4) & 3;
    const int n16  = t & 15;
    const int q0   = blockIdx.x * 128;
    const int h    = blockIdx.y;
    const int b    = blockIdx.z;
    const int kh   = h >> 2;

    const int sr = t >> 2;            // 0..63 staging row
    const int sc = (t & 3) * 8;       // K staging col
    const int vc = (t & 3) * 16;      // V staging col

    // loop-invariant Q A-frags from global (pre-scaled by 0.125*log2e)
    short8 qf[2][2];
#pragma unroll
    for (int m = 0; m < 2; ++m)
#pragma unroll
        for (int kc = 0; kc < 2; ++kc)
            qf[m][kc] = *(const short8*)(QKVb +
                (size_t)(b * SS + q0 + wave * 32 + m * 16 + n16) * QKD +
                h * HD + kc * 32 + quad * 8);

    float l_p[2][4] = {};             // per-lane partial row sums
    f32x4 acc_o[2][4] = {};

    const ushort_t* Kbase = QKVb + (size_t)(b * SS) * QKD + DD + kh * HD;
    const ushort_t* Vbase = VT + ((size_t)b * KVD + kh * 64) * SS;

    for (int kt = 0; kt < SS / 64; ++kt) {
        const int k0 = kt * 64;
        __syncthreads();   // prev-tile readers of Ks/Vs done
        {
            const ushort_t* Kg = Kbase + (size_t)(k0 + sr) * QKD + sc;
            uint4 kv0 = *(const uint4*)(Kg);
            uint4 kv1 = *(const uint4*)(Kg + 32);
            *(uint2*)&Ks[sr][sc]          = make_uint2(kv0.x, kv0.y);
            *(uint2*)&Ks[sr][sc + 4]      = make_uint2(kv0.z, kv0.w);
            *(uint2*)&Ks[sr][sc + 32]     = make_uint2(kv1.x, kv1.y);
            *(uint2*)&Ks[sr][sc + 36]     = make_uint2(kv1.z, kv1.w);
            const ushort_t* Vg = Vbase + (size_t)sr * SS + k0 + vc;
            uint4 vv0 = *(const uint4*)(Vg);
            uint4 vv1 = *(const uint4*)(Vg + 8);
            *(uint2*)&Vs[sr][vc]          = make_uint2(vv0.x, vv0.y);
            *(uint2*)&Vs[sr][vc + 4]      = make_uint2(vv0.z, vv0.w);
            *(uint2*)&Vs[sr][vc + 8]      = make_uint2(vv1.x, vv1.y);
            *(uint2*)&Vs[sr][vc + 12]     = make_uint2(vv1.z, vv1.w);
        }
        __syncthreads();

        // ---- QK^T: S[32q][64k] per wave ----
        f32x4 s_acc[2][4] = {};
#pragma unroll
        for (int kc = 0; kc < 2; ++kc) {
            short8 bf[4];
#pragma unroll
            for (int jj = 0; jj < 4; ++jj)
                bf[jj] = lds_frag8(&Ks[jj * 16 + n16][kc * 32 + quad * 8]);
#pragma unroll
            for (int m = 0; m < 2; ++m)
#pragma unroll
                for (int jj = 0; jj < 4; ++jj)
                    s_acc[m][jj] = __builtin_amdgcn_mfma_f32_16x16x32_bf16(
                        qf[m][kc], bf[jj], s_acc[m][jj], 0, 0, 0);
        }

        // ---- p = 2^s; accumulate partial l; P -> wave-private LDS rows ----
#pragma unroll
        for (int m = 0; m < 2; ++m)
#pragma unroll
            for (int r = 0; r < 4; ++r) {
                float p0 = EXP2(s_acc[m][0][r]);
                float p1 = EXP2(s_acc[m][1][r]);
                float p2 = EXP2(s_acc[m][2][r]);
                float p3 = EXP2(s_acc[m][3][r]);
                ushort_t* pr = &Ps[wave * 32 + m * 16 + quad * 4 + r][n16];
                pr[0]  = f2bf_trunc(p0);
                pr[16] = f2bf_trunc(p1);
                pr[32] = f2bf_trunc(p2);
                pr[48] = f2bf_trunc(p3);
                l_p[m][r] += (p0 + p1) + (p2 + p3);
            }

        // ---- PV (Ps rows wave-private; same-wave RAW via lgkmcnt) ----
#pragma unroll
        for (int kc = 0; kc < 2; ++kc) {
            short8 vb[4];
#pragma unroll
            for (int dd = 0; dd < 4; ++dd)
                vb[dd] = lds_frag8(&Vs[dd * 16 + n16][kc * 32 + quad * 8]);
#pragma unroll
            for (int m = 0; m < 2; ++m) {
                short8 pa = lds_frag8(&Ps[wave * 32 + m * 16 + n16][kc * 32 + quad * 8]);
#pragma unroll
                for (int dd = 0; dd < 4; ++dd)
                    acc_o[m][dd] = __builtin_amdgcn_mfma_f32_16x16x32_bf16(
                        pa, vb[dd], acc_o[m][dd], 0, 0, 0);
            }
        }
    }

    // ---- epilogue: one lane-reduction of l, then O/l ----
#pragma unroll
    for (int m = 0; m < 2; ++m) {
        float inv[4];
#pragma unroll
        for (int r = 0; r < 4; ++r) {
            float s = l_p[m][r];
#pragma unroll
            for (int msk = 1; msk < 16; msk <<= 1)
                s += __shfl_xor(s, msk);
            inv[r] = 1.0f / s;
        }
#pragma unroll
        for (int dd = 0; dd < 4; ++dd)
#pragma unroll
            for (int r = 0; r < 4; ++r) {
                int q = q0 + wave * 32 + m * 16 + quad * 4 + r;
                AOb[(size_t)(b * SS + q) * DD + h * HD + dd * 16 + n16] =
                    f2bf(acc_o[m][dd][r] * inv[r]);
            }
    }
}

// ---------------------------------------------------------------------------
// K4: MFMA out-proj.  out[MM][DD](fp32) = AOb @ Wot^T + bo + HS.
// 64m x 128n tiles, grid (DD/128=12) x (MM/64=64) = 768 = exactly 3/CU.
// ---------------------------------------------------------------------------
__global__ __launch_bounds__(256) void k_out_mfma(const ushort_t* __restrict__ AOb,
                                                  const ushort_t* __restrict__ Wot,
                                                  const float* __restrict__ bo,
                                                  const float* __restrict__ HS,
                                                  float* __restrict__ out)
{
    __shared__ ushort_t As[64][32];    // AOb rows (m)
    __shared__ ushort_t Bs[128][32];   // Wot rows (n)
    const int t = threadIdx.x, lane = t & 63, wave = t >> 6;
    const int n16 = lane & 15, quad = lane >> 4;
    const int wr = wave >> 1, wc = wave & 1;
    const int n0 = blockIdx.x * 128;
    const int m0 = blockIdx.y * 64;

    const int srow = lane >> 2;
    const int scol = (lane & 3) * 8;
    const size_t aoff  = (size_t)(m0 + wave * 16 + srow) * DD + scol;
    const size_t boff0 = (size_t)(n0 + wave * 32 + srow) * DD + scol;
    const size_t boff1 = boff0 + (size_t)16 * DD;
    ushort_t* lA  = &As[wave * 16][0];
    ushort_t* lB0 = &Bs[wave * 32][0];
    ushort_t* lB1 = &Bs[wave * 32 + 16][0];

    f32x4 acc[2][4] = {};
    for (int k0 = 0; k0 < DD; k0 += 32) {
        __syncthreads();
        glds16(AOb + aoff  + k0, lA);
        glds16(Wot + boff0 + k0, lB0);
        glds16(Wot + boff1 + k0, lB1);
        __syncthreads();
        short8 af[2], bf8[4];
#pragma unroll
        for (int i = 0; i < 2; ++i) af[i]  = *(const short8*)&As[wr * 32 + i * 16 + n16][quad * 8];
#pragma unroll
        for (int j = 0; j < 4; ++j) bf8[j] = *(const short8*)&Bs[wc * 64 + j * 16 + n16][quad * 8];
#pragma unroll
        for (int i = 0; i < 2; ++i)
#pragma unroll
            for (int j = 0; j < 4; ++j)
                acc[i][j] = __builtin_amdgcn_mfma_f32_16x16x32_bf16(af[i], bf8[j], acc[i][j], 0, 0, 0);
    }

    const int colb = n0 + wc * 64 + n16;
    float bo4[4];
#pragma unroll
    for (int j = 0; j < 4; ++j) bo4[j] = bo[colb + j * 16];
#pragma unroll
    for (int i = 0; i < 2; ++i) {
#pragma unroll
        for (int r = 0; r < 4; ++r) {
            const int row = m0 + wr * 32 + i * 16 + quad * 4 + r;
            float* op = out + (size_t)row * DD + colb;
            const float* hp = HS + (size_t)row * DD + colb;
#pragma unroll
            for (int j = 0; j < 4; ++j)
                op[j * 16] = acc[i][j][r] + bo4[j] + hp[j * 16];
        }
    }
}

extern "C" void kernel_launch(void* const* d_in, const int* in_sizes, int n_in,
                              void* d_out, int out_size, void* d_ws, size_t ws_size,
                              hipStream_t stream)
{
    const float* HS   = (const float*)d_in[0];
    const float* cosb = (const float*)d_in[1];
    const float* sinb = (const float*)d_in[2];
    const float* Wq   = (const float*)d_in[3];
    const float* Wk   = (const float*)d_in[4];
    const float* Wv   = (const float*)d_in[5];
    const float* Wo   = (const float*)d_in[6];
    const float* bo   = (const float*)d_in[7];
    float* out = (float*)d_out;

    ushort_t* Xbf  = (ushort_t*)d_ws;                  // [MM][DD]
    ushort_t* QKVb = Xbf  + (size_t)MM * DD;           // [MM][QKD]
    ushort_t* AOb  = QKVb + (size_t)MM * QKD;          // [MM][DD]
    ushort_t* Wqt  = AOb  + (size_t)MM * DD;           // [DD][DD]
    ushort_t* Wkt  = Wqt  + (size_t)DD * DD;           // [KVD][DD]
    ushort_t* Wvt  = Wkt  + (size_t)KVD * DD;          // [KVD][DD]
    ushort_t* Wot  = Wvt  + (size_t)KVD * DD;          // [DD][DD]
    ushort_t* VT   = Wot  + (size_t)DD * DD;           // [BB][KVD][SS]

    const int nprep = NCVT + 2304 + 576 + 576 + 2304;
    k_prep    <<<dim3(nprep), 256, 0, stream>>>(HS, Wq, Wk, Wv, Wo,
                                                Xbf, Wqt, Wkt, Wvt, Wot);
    k_proj    <<<dim3(480 + 192), 256, 0, stream>>>(Xbf, Wqt, Wkt, Wvt,
                                                    cosb, sinb, QKVb, VT);
    k_attn    <<<dim3(SS / 128, HEADS, BB), 256, 0, stream>>>(QKVb, VT, AOb);
    k_out_mfma<<<dim3(DD / 128, MM / 64),   256, 0, stream>>>(AOb, Wot, bo, HS, out);
}